// Round 6
// baseline (1152.365 us; speedup 1.0000x reference)
//
#include <hip/hip_runtime.h>
#include <hip/hip_bf16.h>

// Problem constants (fixed by the reference setup)
#define N_VERTS   100000
#define N_HGE     10000
#define N_INC     1600000
#define N_EDGES   1600000
#define C_IN      256
#define C_MID     128
#define C_OUT     64
#define NEG       0.2f

// Radix-partition parameters
#define ESHIFT 8                 // 256 hyperedges per bucket
#define NB_E   40                // ceil(10000/256)
#define VSHIFT 11                // 2048 vertices per bucket
#define NB_V   49                // ceil(100000/2048)
#define PAIRS_PER_BLOCK 2048     // 256 threads x 8
#define BPB_E 20                 // phase-B blocks per E-bucket
#define BPB_V 16                 // phase-B blocks per V-bucket

// ---------------------------------------------------------------------------
// MLP: h = leaky_relu(x @ W1 + b1) @ W2 + b2   (all f32)
// 32 vertices per block, 256 threads = 64 j-lanes x 4 vert-groups (8 verts).
// ---------------------------------------------------------------------------
#define VPB 32
__global__ __launch_bounds__(256) void
mlp_kernel(const float* __restrict__ x, const float* __restrict__ W1,
           const float* __restrict__ b1, const float* __restrict__ W2,
           const float* __restrict__ b2, float* __restrict__ h) {
    __shared__ float xs[VPB][C_IN];    // 32 KB
    __shared__ float mid[VPB][C_MID];  // 16 KB
    const int t  = threadIdx.x;
    const int v0 = blockIdx.x * VPB;
    const int j0 = t & 63;
    const int vbase = (t >> 6) * 8;

    {
        const float* xp = x + (size_t)v0 * C_IN;
#pragma unroll
        for (int it = 0; it < 8; ++it) {
            const int idx = it * 256 + t;       // float4 index
            const int row = idx >> 6;
            const int c4  = (idx & 63) * 4;
            *(float4*)&xs[row][c4] = *(const float4*)&xp[(size_t)row * C_IN + c4];
        }
    }
    __syncthreads();

    {   // layer 1
        float acc0[8], acc1[8];
        const float bA = b1[j0], bB = b1[j0 + 64];
#pragma unroll
        for (int i = 0; i < 8; ++i) { acc0[i] = bA; acc1[i] = bB; }
        for (int k = 0; k < C_IN; k += 4) {
            float4 xv[8];
#pragma unroll
            for (int i = 0; i < 8; ++i)
                xv[i] = *(const float4*)&xs[vbase + i][k];
#pragma unroll
            for (int kk = 0; kk < 4; ++kk) {
                const float w0 = W1[(k + kk) * C_MID + j0];
                const float w1 = W1[(k + kk) * C_MID + j0 + 64];
#pragma unroll
                for (int i = 0; i < 8; ++i) {
                    const float xvv = kk == 0 ? xv[i].x : kk == 1 ? xv[i].y
                                   : kk == 2 ? xv[i].z : xv[i].w;
                    acc0[i] += xvv * w0;
                    acc1[i] += xvv * w1;
                }
            }
        }
#pragma unroll
        for (int i = 0; i < 8; ++i) {
            const float a = acc0[i], b = acc1[i];
            mid[vbase + i][j0]      = a > 0.f ? a : NEG * a;
            mid[vbase + i][j0 + 64] = b > 0.f ? b : NEG * b;
        }
    }
    __syncthreads();

    {   // layer 2
        float acc[8];
        const float bias = b2[j0];
#pragma unroll
        for (int i = 0; i < 8; ++i) acc[i] = bias;
        for (int k = 0; k < C_MID; k += 4) {
            float4 xv[8];
#pragma unroll
            for (int i = 0; i < 8; ++i)
                xv[i] = *(const float4*)&mid[vbase + i][k];
#pragma unroll
            for (int kk = 0; kk < 4; ++kk) {
                const float w0 = W2[(k + kk) * C_OUT + j0];
#pragma unroll
                for (int i = 0; i < 8; ++i) {
                    const float xvv = kk == 0 ? xv[i].x : kk == 1 ? xv[i].y
                                   : kk == 2 ? xv[i].z : xv[i].w;
                    acc[i] += xvv * w0;
                }
            }
        }
#pragma unroll
        for (int i = 0; i < 8; ++i)
            h[(size_t)(v0 + vbase + i) * C_OUT + j0] = acc[i];
    }
}

// ---------------------------------------------------------------------------
// CSR build: count degrees for all three groupings in one pass.
// ---------------------------------------------------------------------------
__global__ void count_kernel(const int* __restrict__ hg_v, const int* __restrict__ hg_e,
                             const int* __restrict__ g_dst,
                             int* __restrict__ deg_e, int* __restrict__ deg_vhg,
                             int* __restrict__ deg_vg) {
    const int i = blockIdx.x * blockDim.x + threadIdx.x;
    if (i >= N_INC) return;
    atomicAdd(&deg_e[hg_e[i]], 1);
    atomicAdd(&deg_vhg[hg_v[i]], 1);
    atomicAdd(&deg_vg[g_dst[i]], 1);
}

// Three independent single-block exclusive scans in ONE dispatch (3 blocks).
__global__ __launch_bounds__(1024) void
scan3_kernel(const int* __restrict__ deg_e,   int* __restrict__ off_e,
             const int* __restrict__ deg_vhg, int* __restrict__ off_vhg,
             const int* __restrict__ deg_vg,  int* __restrict__ off_vg) {
    __shared__ int sums[1024];
    const int* cnt; int* off; int n;
    if (blockIdx.x == 0)      { cnt = deg_e;   off = off_e;   n = N_HGE;   }
    else if (blockIdx.x == 1) { cnt = deg_vhg; off = off_vhg; n = N_VERTS; }
    else                      { cnt = deg_vg;  off = off_vg;  n = N_VERTS; }

    const int t = threadIdx.x;
    const int chunk = (n + 1023) / 1024;
    const int lo = t * chunk;
    const int hi = min(lo + chunk, n);
    int s = 0;
    for (int i = lo; i < hi; ++i) s += cnt[i];
    sums[t] = s;
    __syncthreads();
    for (int d = 1; d < 1024; d <<= 1) {
        int v = (t >= d) ? sums[t - d] : 0;
        __syncthreads();
        sums[t] += v;
        __syncthreads();
    }
    int run = (t > 0) ? sums[t - 1] : 0;
    for (int i = lo; i < hi; ++i) { off[i] = run; run += cnt[i]; }
}

// ---------------------------------------------------------------------------
// Phase A: radix partition. Each block handles 2048 pairs for all 3 tables.
// LDS histogram -> one global atomic per (block,bucket) reserves a dense run
// in the bucket's record region -> append (dst,payload) records. Writes are
// dense per run => ~1x write amplification.
// Bucket record-region base = off[b<<shift] (bucket = contiguous dst range).
// ---------------------------------------------------------------------------
__global__ __launch_bounds__(256) void
partitionA_kernel(const int* __restrict__ hg_v, const int* __restrict__ hg_e,
                  const int* __restrict__ g_src, const int* __restrict__ g_dst,
                  const int* __restrict__ off_e, const int* __restrict__ off_vhg,
                  const int* __restrict__ off_vg,
                  int* __restrict__ bcur_e, int* __restrict__ bcur_vhg,
                  int* __restrict__ bcur_vg,
                  uint2* __restrict__ rec_e, uint2* __restrict__ rec_vhg,
                  uint2* __restrict__ rec_vg) {
    __shared__ int hist[NB_V];
    __shared__ int gb[NB_V];
    __shared__ int bb[NB_V];
    const int t  = threadIdx.x;
    const int i0 = blockIdx.x * PAIRS_PER_BLOCK + t;

    for (int table = 0; table < 3; ++table) {
        const int *dsts, *pays, *off;
        int *bcur; uint2* rec;
        int shift, nb;
        if (table == 0)      { dsts = hg_e;  pays = hg_v;  off = off_e;
                               bcur = bcur_e;   rec = rec_e;   shift = ESHIFT; nb = NB_E; }
        else if (table == 1) { dsts = hg_v;  pays = hg_e;  off = off_vhg;
                               bcur = bcur_vhg; rec = rec_vhg; shift = VSHIFT; nb = NB_V; }
        else                 { dsts = g_dst; pays = g_src; off = off_vg;
                               bcur = bcur_vg;  rec = rec_vg;  shift = VSHIFT; nb = NB_V; }

        if (t < nb) hist[t] = 0;
        __syncthreads();

        int d[8], p[8], bk[8], rk[8];
#pragma unroll
        for (int q = 0; q < 8; ++q) {
            const int i = i0 + q * 256;
            if (i < N_INC) {
                d[q]  = dsts[i];
                p[q]  = pays[i];
                bk[q] = d[q] >> shift;
                rk[q] = atomicAdd(&hist[bk[q]], 1);
            } else bk[q] = -1;
        }
        __syncthreads();

        if (t < nb) {
            gb[t] = atomicAdd(&bcur[t], hist[t]);
            bb[t] = off[t << shift];
        }
        __syncthreads();

#pragma unroll
        for (int q = 0; q < 8; ++q) {
            if (bk[q] >= 0) {
                const int pos = bb[bk[q]] + gb[bk[q]] + rk[q];
                rec[pos] = make_uint2((unsigned)d[q], (unsigned)p[q]);
            }
        }
        __syncthreads();   // hist/gb/bb reused next table
    }
}

// ---------------------------------------------------------------------------
// Phase B: local fill. Blocks partition each bucket's record run; slot writes
// land in that bucket's small (~130-330 KB) slot region => L2-hot.
// ---------------------------------------------------------------------------
#define GRID_B (NB_E * BPB_E + 2 * NB_V * BPB_V)
__global__ __launch_bounds__(256) void
partitionB_kernel(const uint2* __restrict__ rec_e, const uint2* __restrict__ rec_vhg,
                  const uint2* __restrict__ rec_vg,
                  const int* __restrict__ off_e, const int* __restrict__ off_vhg,
                  const int* __restrict__ off_vg,
                  int* __restrict__ cur_e, int* __restrict__ cur_vhg,
                  int* __restrict__ cur_vg,
                  int* __restrict__ slot_e, int* __restrict__ slot_vhg,
                  int* __restrict__ slot_vg) {
    int blk = blockIdx.x;
    const uint2* rec; const int* off; int* cur; int* slot;
    int b, c, shift, nb, ndst, bpb;
    if (blk < NB_E * BPB_E) {
        rec = rec_e; off = off_e; cur = cur_e; slot = slot_e;
        shift = ESHIFT; nb = NB_E; ndst = N_HGE; bpb = BPB_E;
        b = blk / BPB_E; c = blk % BPB_E;
    } else if (blk < NB_E * BPB_E + NB_V * BPB_V) {
        blk -= NB_E * BPB_E;
        rec = rec_vhg; off = off_vhg; cur = cur_vhg; slot = slot_vhg;
        shift = VSHIFT; nb = NB_V; ndst = N_VERTS; bpb = BPB_V;
        b = blk / BPB_V; c = blk % BPB_V;
    } else {
        blk -= NB_E * BPB_E + NB_V * BPB_V;
        rec = rec_vg; off = off_vg; cur = cur_vg; slot = slot_vg;
        shift = VSHIFT; nb = NB_V; ndst = N_VERTS; bpb = BPB_V;
        b = blk / BPB_V; c = blk % BPB_V;
    }
    const int bstart = off[b << shift];
    const int nxt    = (b + 1) << shift;
    const int bend   = (nxt >= ndst) ? N_INC : off[nxt];
    const int bcnt   = bend - bstart;
    const int chunk  = (bcnt + bpb - 1) / bpb;
    const int s      = bstart + c * chunk;
    const int e      = min(s + chunk, bend);
    for (int i = s + (int)threadIdx.x; i < e; i += 256) {
        const uint2 r = rec[i];
        const int dst = (int)r.x;
        const int pos = off[dst] + atomicAdd(&cur[dst], 1);
        slot[pos] = (int)r.y;
    }
}

// ---------------------------------------------------------------------------
// v2e gather: one wave per hyperedge, lane = channel.
// ---------------------------------------------------------------------------
__global__ void gather_e_kernel(const int* __restrict__ slot, const int* __restrict__ off,
                                const int* __restrict__ deg, const float* __restrict__ h,
                                float* __restrict__ e_feat) {
    const int wid  = (blockIdx.x * blockDim.x + threadIdx.x) >> 6;
    const int lane = threadIdx.x & 63;
    if (wid >= N_HGE) return;
    const int n    = deg[wid];
    const int base = off[wid];
    float acc = 0.f;
    int j = 0;
    for (; j + 4 <= n; j += 4) {
        const int v0 = slot[base + j + 0];
        const int v1 = slot[base + j + 1];
        const int v2 = slot[base + j + 2];
        const int v3 = slot[base + j + 3];
        const float r0 = h[(size_t)v0 * C_OUT + lane];
        const float r1 = h[(size_t)v1 * C_OUT + lane];
        const float r2 = h[(size_t)v2 * C_OUT + lane];
        const float r3 = h[(size_t)v3 * C_OUT + lane];
        acc += (r0 + r1) + (r2 + r3);
    }
    for (; j < n; ++j)
        acc += h[(size_t)slot[base + j] * C_OUT + lane];
    e_feat[(size_t)wid * C_OUT + lane] = acc / fmaxf((float)n, 1.f);
}

// ---------------------------------------------------------------------------
// Fused per-vertex: x_hg gather (over e_feat) + x_g gather (over h) +
// softmax-weighted fuse + leaky -> out. One wave per vertex, lane = channel.
// ---------------------------------------------------------------------------
__global__ void vertex_out_kernel(const int* __restrict__ slot_vhg,
                                  const int* __restrict__ off_vhg,
                                  const int* __restrict__ deg_vhg,
                                  const int* __restrict__ slot_vg,
                                  const int* __restrict__ off_vg,
                                  const int* __restrict__ deg_vg,
                                  const float* __restrict__ e_feat,
                                  const float* __restrict__ h,
                                  const float* __restrict__ w,
                                  float* __restrict__ out) {
    const int wid  = (blockIdx.x * blockDim.x + threadIdx.x) >> 6;
    const int lane = threadIdx.x & 63;
    if (wid >= N_VERTS) return;

    float acc_hg = 0.f;
    {
        const int n = deg_vhg[wid];
        const int base = off_vhg[wid];
        int j = 0;
        for (; j + 4 <= n; j += 4) {
            const int e0 = slot_vhg[base + j + 0];
            const int e1 = slot_vhg[base + j + 1];
            const int e2 = slot_vhg[base + j + 2];
            const int e3 = slot_vhg[base + j + 3];
            const float r0 = e_feat[(size_t)e0 * C_OUT + lane];
            const float r1 = e_feat[(size_t)e1 * C_OUT + lane];
            const float r2 = e_feat[(size_t)e2 * C_OUT + lane];
            const float r3 = e_feat[(size_t)e3 * C_OUT + lane];
            acc_hg += (r0 + r1) + (r2 + r3);
        }
        for (; j < n; ++j)
            acc_hg += e_feat[(size_t)slot_vhg[base + j] * C_OUT + lane];
        acc_hg /= fmaxf((float)n, 1.f);
    }

    float acc_g = 0.f;
    {
        const int n = deg_vg[wid];
        const int base = off_vg[wid];
        int j = 0;
        for (; j + 4 <= n; j += 4) {
            const int v0 = slot_vg[base + j + 0];
            const int v1 = slot_vg[base + j + 1];
            const int v2 = slot_vg[base + j + 2];
            const int v3 = slot_vg[base + j + 3];
            const float r0 = h[(size_t)v0 * C_OUT + lane];
            const float r1 = h[(size_t)v1 * C_OUT + lane];
            const float r2 = h[(size_t)v2 * C_OUT + lane];
            const float r3 = h[(size_t)v3 * C_OUT + lane];
            acc_g += (r0 + r1) + (r2 + r3);
        }
        for (; j < n; ++j)
            acc_g += h[(size_t)slot_vg[base + j] * C_OUT + lane];
        acc_g /= fmaxf((float)n, 1.f);
    }

    const float w0 = w[0], w1 = w[1];
    const float m  = fmaxf(w0, w1);
    const float e0 = __expf(w0 - m), e1 = __expf(w1 - m);
    const float sw0 = e0 / (e0 + e1), sw1 = e1 / (e0 + e1);

    const float hv = h[(size_t)wid * C_OUT + lane];
    float o = sw0 * 0.5f * (acc_g + acc_hg) + sw1 * hv;
    o = o > 0.f ? o : NEG * o;
    out[(size_t)wid * C_OUT + lane] = o;
}

// ---------------------------------------------------------------------------
extern "C" void kernel_launch(void* const* d_in, const int* in_sizes, int n_in,
                              void* d_out, int out_size, void* d_ws, size_t ws_size,
                              hipStream_t stream) {
    const float* x    = (const float*)d_in[0];
    const float* W1   = (const float*)d_in[1];
    const float* b1   = (const float*)d_in[2];
    const float* W2   = (const float*)d_in[3];
    const float* b2   = (const float*)d_in[4];
    const float* w    = (const float*)d_in[5];
    const int*  hg_v  = (const int*)d_in[6];
    const int*  hg_e  = (const int*)d_in[7];
    const int*  g_src = (const int*)d_in[8];
    const int*  g_dst = (const int*)d_in[9];
    float* out = (float*)d_out;

    // ---- workspace layout ----
    // Region R (reused): rec arrays during CSR build, then h + e_feat.
    uint2* rec_e   = (uint2*)d_ws;                 // N_INC   (12.8 MB)
    uint2* rec_vhg = rec_e   + N_INC;              // N_INC   (12.8 MB)
    uint2* rec_vg  = rec_vhg + N_INC;              // N_EDGES (12.8 MB)
    float* h       = (float*)d_ws;                 // N_VERTS*64 (25.6 MB) - after B
    float* e_feat  = h + (size_t)N_VERTS * C_OUT;  // N_HGE*64   (2.56 MB) - after B

    int* slot_e    = (int*)(rec_vg + N_EDGES);     // N_INC
    int* slot_vhg  = slot_e   + N_INC;             // N_INC
    int* slot_vg   = slot_vhg + N_INC;             // N_EDGES
    // zeroed int region:
    int* deg_e     = slot_vg  + N_EDGES;           // N_HGE
    int* cur_e     = deg_e    + N_HGE;             // N_HGE
    int* deg_vhg   = cur_e    + N_HGE;             // N_VERTS
    int* cur_vhg   = deg_vhg  + N_VERTS;           // N_VERTS
    int* deg_vg    = cur_vhg  + N_VERTS;           // N_VERTS
    int* cur_vg    = deg_vg   + N_VERTS;           // N_VERTS
    int* bcur_e    = cur_vg   + N_VERTS;           // NB_E
    int* bcur_vhg  = bcur_e   + NB_E;              // NB_V
    int* bcur_vg   = bcur_vhg + NB_V;              // NB_V
    // not zeroed:
    int* off_e     = bcur_vg  + NB_V;              // N_HGE
    int* off_vhg   = off_e    + N_HGE;             // N_VERTS
    int* off_vg    = off_vhg  + N_VERTS;           // N_VERTS

    const size_t zero_elems = 2 * (size_t)N_HGE + 4 * (size_t)N_VERTS
                            + NB_E + 2 * NB_V;
    hipMemsetAsync(deg_e, 0, zero_elems * sizeof(int), stream);

    // ---- CSR build ----
    const int pair_blocks = (N_INC + 255) / 256;
    count_kernel<<<pair_blocks, 256, 0, stream>>>(hg_v, hg_e, g_dst,
                                                  deg_e, deg_vhg, deg_vg);
    scan3_kernel<<<3, 1024, 0, stream>>>(deg_e, off_e, deg_vhg, off_vhg,
                                         deg_vg, off_vg);
    const int partA_blocks = (N_INC + PAIRS_PER_BLOCK - 1) / PAIRS_PER_BLOCK;
    partitionA_kernel<<<partA_blocks, 256, 0, stream>>>(
        hg_v, hg_e, g_src, g_dst, off_e, off_vhg, off_vg,
        bcur_e, bcur_vhg, bcur_vg, rec_e, rec_vhg, rec_vg);
    partitionB_kernel<<<GRID_B, 256, 0, stream>>>(
        rec_e, rec_vhg, rec_vg, off_e, off_vhg, off_vg,
        cur_e, cur_vhg, cur_vg, slot_e, slot_vhg, slot_vg);

    // ---- MLP (after B: h aliases rec region) ----
    mlp_kernel<<<N_VERTS / VPB, 256, 0, stream>>>(x, W1, b1, W2, b2, h);

    // ---- v2e gather ----
    const int ge_blocks = (int)(((size_t)N_HGE * 64 + 255) / 256);
    gather_e_kernel<<<ge_blocks, 256, 0, stream>>>(slot_e, off_e, deg_e, h, e_feat);

    // ---- fused e2v + graph gather + finalize ----
    const int vo_blocks = (int)(((size_t)N_VERTS * 64 + 255) / 256);
    vertex_out_kernel<<<vo_blocks, 256, 0, stream>>>(slot_vhg, off_vhg, deg_vhg,
                                                     slot_vg, off_vg, deg_vg,
                                                     e_feat, h, w, out);
}

// Round 7
// 970.231 us; speedup vs baseline: 1.1877x; 1.1877x over previous
//
#include <hip/hip_runtime.h>
#include <hip/hip_bf16.h>

// Problem constants (fixed by the reference setup)
#define N_VERTS   100000
#define N_HGE     10000
#define N_INC     1600000
#define N_EDGES   1600000
#define C_IN      256
#define C_MID     128
#define C_OUT     64
#define NEG       0.2f

// Radix-partition parameters.
// Buckets sized so one bucket's slots fit in 64KB LDS:
//   E-buckets: 64 hyperedges,  mean 10240 slots (cap 16384)
//   V-buckets: 512 vertices,   mean  8192 slots (cap 16384)
#define EBSHIFT 6
#define NB_E    157              // ceil(10000/64)
#define VBSHIFT 9
#define NB_V    196              // ceil(100000/512)
#define NB_MAX  196
#define PAIRS_PER_BLOCK 4096     // 256 threads x 16
#define QP 16
#define BUCKET_CAP 16384

// ---------------------------------------------------------------------------
// MLP: h = leaky_relu(x @ W1 + b1) @ W2 + b2   (all f32)
// 32 vertices per block, 256 threads = 64 j-lanes x 4 vert-groups (8 verts).
// ---------------------------------------------------------------------------
#define VPB 32
__global__ __launch_bounds__(256) void
mlp_kernel(const float* __restrict__ x, const float* __restrict__ W1,
           const float* __restrict__ b1, const float* __restrict__ W2,
           const float* __restrict__ b2, float* __restrict__ h) {
    __shared__ float xs[VPB][C_IN];    // 32 KB
    __shared__ float mid[VPB][C_MID];  // 16 KB
    const int t  = threadIdx.x;
    const int v0 = blockIdx.x * VPB;
    const int j0 = t & 63;
    const int vbase = (t >> 6) * 8;

    {
        const float* xp = x + (size_t)v0 * C_IN;
#pragma unroll
        for (int it = 0; it < 8; ++it) {
            const int idx = it * 256 + t;       // float4 index
            const int row = idx >> 6;
            const int c4  = (idx & 63) * 4;
            *(float4*)&xs[row][c4] = *(const float4*)&xp[(size_t)row * C_IN + c4];
        }
    }
    __syncthreads();

    {   // layer 1
        float acc0[8], acc1[8];
        const float bA = b1[j0], bB = b1[j0 + 64];
#pragma unroll
        for (int i = 0; i < 8; ++i) { acc0[i] = bA; acc1[i] = bB; }
        for (int k = 0; k < C_IN; k += 4) {
            float4 xv[8];
#pragma unroll
            for (int i = 0; i < 8; ++i)
                xv[i] = *(const float4*)&xs[vbase + i][k];
#pragma unroll
            for (int kk = 0; kk < 4; ++kk) {
                const float w0 = W1[(k + kk) * C_MID + j0];
                const float w1 = W1[(k + kk) * C_MID + j0 + 64];
#pragma unroll
                for (int i = 0; i < 8; ++i) {
                    const float xvv = kk == 0 ? xv[i].x : kk == 1 ? xv[i].y
                                   : kk == 2 ? xv[i].z : xv[i].w;
                    acc0[i] += xvv * w0;
                    acc1[i] += xvv * w1;
                }
            }
        }
#pragma unroll
        for (int i = 0; i < 8; ++i) {
            const float a = acc0[i], b = acc1[i];
            mid[vbase + i][j0]      = a > 0.f ? a : NEG * a;
            mid[vbase + i][j0 + 64] = b > 0.f ? b : NEG * b;
        }
    }
    __syncthreads();

    {   // layer 2
        float acc[8];
        const float bias = b2[j0];
#pragma unroll
        for (int i = 0; i < 8; ++i) acc[i] = bias;
        for (int k = 0; k < C_MID; k += 4) {
            float4 xv[8];
#pragma unroll
            for (int i = 0; i < 8; ++i)
                xv[i] = *(const float4*)&mid[vbase + i][k];
#pragma unroll
            for (int kk = 0; kk < 4; ++kk) {
                const float w0 = W2[(k + kk) * C_OUT + j0];
#pragma unroll
                for (int i = 0; i < 8; ++i) {
                    const float xvv = kk == 0 ? xv[i].x : kk == 1 ? xv[i].y
                                   : kk == 2 ? xv[i].z : xv[i].w;
                    acc[i] += xvv * w0;
                }
            }
        }
#pragma unroll
        for (int i = 0; i < 8; ++i)
            h[(size_t)(v0 + vbase + i) * C_OUT + j0] = acc[i];
    }
}

// ---------------------------------------------------------------------------
// CSR build: count degrees for all three groupings in one pass.
// ---------------------------------------------------------------------------
__global__ void count_kernel(const int* __restrict__ hg_v, const int* __restrict__ hg_e,
                             const int* __restrict__ g_dst,
                             int* __restrict__ deg_e, int* __restrict__ deg_vhg,
                             int* __restrict__ deg_vg) {
    const int i = blockIdx.x * blockDim.x + threadIdx.x;
    if (i >= N_INC) return;
    atomicAdd(&deg_e[hg_e[i]], 1);
    atomicAdd(&deg_vhg[hg_v[i]], 1);
    atomicAdd(&deg_vg[g_dst[i]], 1);
}

// Three independent single-block exclusive scans in ONE dispatch (3 blocks).
__global__ __launch_bounds__(1024) void
scan3_kernel(const int* __restrict__ deg_e,   int* __restrict__ off_e,
             const int* __restrict__ deg_vhg, int* __restrict__ off_vhg,
             const int* __restrict__ deg_vg,  int* __restrict__ off_vg) {
    __shared__ int sums[1024];
    const int* cnt; int* off; int n;
    if (blockIdx.x == 0)      { cnt = deg_e;   off = off_e;   n = N_HGE;   }
    else if (blockIdx.x == 1) { cnt = deg_vhg; off = off_vhg; n = N_VERTS; }
    else                      { cnt = deg_vg;  off = off_vg;  n = N_VERTS; }

    const int t = threadIdx.x;
    const int chunk = (((n + 1023) / 1024) + 3) & ~3;   // multiple of 4
    const int lo = t * chunk;
    const int hi = min(lo + chunk, n);
    int s = 0;
    for (int i = lo; i < hi; ++i) s += cnt[i];
    sums[t] = s;
    __syncthreads();
    for (int d = 1; d < 1024; d <<= 1) {
        int v = (t >= d) ? sums[t - d] : 0;
        __syncthreads();
        sums[t] += v;
        __syncthreads();
    }
    int run = (t > 0) ? sums[t - 1] : 0;
    for (int i = lo; i < hi; ++i) { off[i] = run; run += cnt[i]; }
}

// ---------------------------------------------------------------------------
// Phase A: radix partition. Each block handles 4096 pairs for all 3 tables.
// LDS histogram -> one global atomic per (block,bucket) reserves a dense run
// in the bucket's record region -> append (dst,payload) records.
// ---------------------------------------------------------------------------
__global__ __launch_bounds__(256) void
partitionA_kernel(const int* __restrict__ hg_v, const int* __restrict__ hg_e,
                  const int* __restrict__ g_src, const int* __restrict__ g_dst,
                  const int* __restrict__ off_e, const int* __restrict__ off_vhg,
                  const int* __restrict__ off_vg,
                  int* __restrict__ bcur_e, int* __restrict__ bcur_vhg,
                  int* __restrict__ bcur_vg,
                  uint2* __restrict__ rec_e, uint2* __restrict__ rec_vhg,
                  uint2* __restrict__ rec_vg) {
    __shared__ int hist[NB_MAX];
    __shared__ int gb[NB_MAX];
    __shared__ int bb[NB_MAX];
    const int t  = threadIdx.x;
    const int i0 = blockIdx.x * PAIRS_PER_BLOCK + t;

    for (int table = 0; table < 3; ++table) {
        const int *dsts, *pays, *off;
        int *bcur; uint2* rec;
        int shift, nb;
        if (table == 0)      { dsts = hg_e;  pays = hg_v;  off = off_e;
                               bcur = bcur_e;   rec = rec_e;   shift = EBSHIFT; nb = NB_E; }
        else if (table == 1) { dsts = hg_v;  pays = hg_e;  off = off_vhg;
                               bcur = bcur_vhg; rec = rec_vhg; shift = VBSHIFT; nb = NB_V; }
        else                 { dsts = g_dst; pays = g_src; off = off_vg;
                               bcur = bcur_vg;  rec = rec_vg;  shift = VBSHIFT; nb = NB_V; }

        if (t < nb) hist[t] = 0;
        __syncthreads();

        int d[QP], p[QP], bk[QP], rk[QP];
#pragma unroll
        for (int q = 0; q < QP; ++q) {
            const int i = i0 + q * 256;
            if (i < N_INC) {
                d[q]  = dsts[i];
                p[q]  = pays[i];
                bk[q] = d[q] >> shift;
                rk[q] = atomicAdd(&hist[bk[q]], 1);
            } else bk[q] = -1;
        }
        __syncthreads();

        if (t < nb) {
            gb[t] = atomicAdd(&bcur[t], hist[t]);
            bb[t] = off[t << shift];
        }
        __syncthreads();

#pragma unroll
        for (int q = 0; q < QP; ++q) {
            if (bk[q] >= 0) {
                const int pos = bb[bk[q]] + gb[bk[q]] + rk[q];
                rec[pos] = make_uint2((unsigned)d[q], (unsigned)p[q]);
            }
        }
        __syncthreads();   // hist/gb/bb reused next table
    }
}

// ---------------------------------------------------------------------------
// Phase B: one block per bucket. Build the bucket's final slot contents in
// LDS (private to the CU), then stream out dense, coalesced, full lines.
// Write amplification = 1 by construction (no cross-XCD partial lines).
// Slot order within a dst doesn't matter (feeds a sum).
// ---------------------------------------------------------------------------
#define GRID_B (NB_E + 2 * NB_V)
__global__ __launch_bounds__(256) void
partitionB_kernel(const uint2* __restrict__ rec_e, const uint2* __restrict__ rec_vhg,
                  const uint2* __restrict__ rec_vg,
                  const int* __restrict__ off_e, const int* __restrict__ off_vhg,
                  const int* __restrict__ off_vg,
                  int* __restrict__ cur_e, int* __restrict__ cur_vhg,
                  int* __restrict__ cur_vg,
                  int* __restrict__ slot_e, int* __restrict__ slot_vhg,
                  int* __restrict__ slot_vg) {
    __shared__ int slotbuf[BUCKET_CAP];   // 64 KB
    __shared__ int cur_l[1 << VBSHIFT];   // 2 KB

    int blk = blockIdx.x;
    const uint2* rec; const int* off; int* cur; int* slot;
    int b, shift, ndst;
    if (blk < NB_E) {
        rec = rec_e; off = off_e; cur = cur_e; slot = slot_e;
        shift = EBSHIFT; ndst = N_HGE; b = blk;
    } else if (blk < NB_E + NB_V) {
        rec = rec_vhg; off = off_vhg; cur = cur_vhg; slot = slot_vhg;
        shift = VBSHIFT; ndst = N_VERTS; b = blk - NB_E;
    } else {
        rec = rec_vg; off = off_vg; cur = cur_vg; slot = slot_vg;
        shift = VBSHIFT; ndst = N_VERTS; b = blk - NB_E - NB_V;
    }
    const int t      = threadIdx.x;
    const int dlo    = b << shift;
    const int nxt    = (b + 1) << shift;
    const int bstart = off[dlo];
    const int bend   = (nxt >= ndst) ? N_INC : off[nxt];
    const int bcnt   = bend - bstart;
    const int nd     = 1 << shift;

    for (int j = t; j < nd; j += 256) cur_l[j] = 0;
    __syncthreads();

    if (bcnt <= BUCKET_CAP) {
        for (int i = bstart + t; i < bend; i += 256) {
            const uint2 r = rec[i];
            const int dst = (int)r.x;
            const int lpos = (off[dst] - bstart) + atomicAdd(&cur_l[dst - dlo], 1);
            slotbuf[lpos] = (int)r.y;
        }
        __syncthreads();
        for (int i = t; i < bcnt; i += 256)
            slot[bstart + i] = slotbuf[i];
    } else {
        // statistically unreachable fallback (keeps correctness airtight)
        for (int i = bstart + t; i < bend; i += 256) {
            const uint2 r = rec[i];
            const int dst = (int)r.x;
            const int pos = off[dst] + atomicAdd(&cur[dst], 1);
            slot[pos] = (int)r.y;
        }
    }
}

// ---------------------------------------------------------------------------
// v2e gather: one wave per hyperedge, lane = channel.
// ---------------------------------------------------------------------------
__global__ void gather_e_kernel(const int* __restrict__ slot, const int* __restrict__ off,
                                const int* __restrict__ deg, const float* __restrict__ h,
                                float* __restrict__ e_feat) {
    const int wid  = (blockIdx.x * blockDim.x + threadIdx.x) >> 6;
    const int lane = threadIdx.x & 63;
    if (wid >= N_HGE) return;
    const int n    = deg[wid];
    const int base = off[wid];
    float acc = 0.f;
    int j = 0;
    for (; j + 4 <= n; j += 4) {
        const int v0 = slot[base + j + 0];
        const int v1 = slot[base + j + 1];
        const int v2 = slot[base + j + 2];
        const int v3 = slot[base + j + 3];
        const float r0 = h[(size_t)v0 * C_OUT + lane];
        const float r1 = h[(size_t)v1 * C_OUT + lane];
        const float r2 = h[(size_t)v2 * C_OUT + lane];
        const float r3 = h[(size_t)v3 * C_OUT + lane];
        acc += (r0 + r1) + (r2 + r3);
    }
    for (; j < n; ++j)
        acc += h[(size_t)slot[base + j] * C_OUT + lane];
    e_feat[(size_t)wid * C_OUT + lane] = acc / fmaxf((float)n, 1.f);
}

// ---------------------------------------------------------------------------
// Fused per-vertex: x_hg gather (over e_feat) + x_g gather (over h) +
// softmax-weighted fuse + leaky -> out. One wave per vertex, lane = channel.
// ---------------------------------------------------------------------------
__global__ void vertex_out_kernel(const int* __restrict__ slot_vhg,
                                  const int* __restrict__ off_vhg,
                                  const int* __restrict__ deg_vhg,
                                  const int* __restrict__ slot_vg,
                                  const int* __restrict__ off_vg,
                                  const int* __restrict__ deg_vg,
                                  const float* __restrict__ e_feat,
                                  const float* __restrict__ h,
                                  const float* __restrict__ w,
                                  float* __restrict__ out) {
    const int wid  = (blockIdx.x * blockDim.x + threadIdx.x) >> 6;
    const int lane = threadIdx.x & 63;
    if (wid >= N_VERTS) return;

    float acc_hg = 0.f;
    {
        const int n = deg_vhg[wid];
        const int base = off_vhg[wid];
        int j = 0;
        for (; j + 4 <= n; j += 4) {
            const int e0 = slot_vhg[base + j + 0];
            const int e1 = slot_vhg[base + j + 1];
            const int e2 = slot_vhg[base + j + 2];
            const int e3 = slot_vhg[base + j + 3];
            const float r0 = e_feat[(size_t)e0 * C_OUT + lane];
            const float r1 = e_feat[(size_t)e1 * C_OUT + lane];
            const float r2 = e_feat[(size_t)e2 * C_OUT + lane];
            const float r3 = e_feat[(size_t)e3 * C_OUT + lane];
            acc_hg += (r0 + r1) + (r2 + r3);
        }
        for (; j < n; ++j)
            acc_hg += e_feat[(size_t)slot_vhg[base + j] * C_OUT + lane];
        acc_hg /= fmaxf((float)n, 1.f);
    }

    float acc_g = 0.f;
    {
        const int n = deg_vg[wid];
        const int base = off_vg[wid];
        int j = 0;
        for (; j + 4 <= n; j += 4) {
            const int v0 = slot_vg[base + j + 0];
            const int v1 = slot_vg[base + j + 1];
            const int v2 = slot_vg[base + j + 2];
            const int v3 = slot_vg[base + j + 3];
            const float r0 = h[(size_t)v0 * C_OUT + lane];
            const float r1 = h[(size_t)v1 * C_OUT + lane];
            const float r2 = h[(size_t)v2 * C_OUT + lane];
            const float r3 = h[(size_t)v3 * C_OUT + lane];
            acc_g += (r0 + r1) + (r2 + r3);
        }
        for (; j < n; ++j)
            acc_g += h[(size_t)slot_vg[base + j] * C_OUT + lane];
        acc_g /= fmaxf((float)n, 1.f);
    }

    const float w0 = w[0], w1 = w[1];
    const float m  = fmaxf(w0, w1);
    const float e0 = __expf(w0 - m), e1 = __expf(w1 - m);
    const float sw0 = e0 / (e0 + e1), sw1 = e1 / (e0 + e1);

    const float hv = h[(size_t)wid * C_OUT + lane];
    float o = sw0 * 0.5f * (acc_g + acc_hg) + sw1 * hv;
    o = o > 0.f ? o : NEG * o;
    out[(size_t)wid * C_OUT + lane] = o;
}

// ---------------------------------------------------------------------------
extern "C" void kernel_launch(void* const* d_in, const int* in_sizes, int n_in,
                              void* d_out, int out_size, void* d_ws, size_t ws_size,
                              hipStream_t stream) {
    const float* x    = (const float*)d_in[0];
    const float* W1   = (const float*)d_in[1];
    const float* b1   = (const float*)d_in[2];
    const float* W2   = (const float*)d_in[3];
    const float* b2   = (const float*)d_in[4];
    const float* w    = (const float*)d_in[5];
    const int*  hg_v  = (const int*)d_in[6];
    const int*  hg_e  = (const int*)d_in[7];
    const int*  g_src = (const int*)d_in[8];
    const int*  g_dst = (const int*)d_in[9];
    float* out = (float*)d_out;

    // ---- workspace layout ----
    // Region R (reused): rec arrays during CSR build, then h + e_feat.
    uint2* rec_e   = (uint2*)d_ws;                 // N_INC   (12.8 MB)
    uint2* rec_vhg = rec_e   + N_INC;              // N_INC   (12.8 MB)
    uint2* rec_vg  = rec_vhg + N_INC;              // N_EDGES (12.8 MB)
    float* h       = (float*)d_ws;                 // N_VERTS*64 (25.6 MB) - after B
    float* e_feat  = h + (size_t)N_VERTS * C_OUT;  // N_HGE*64   (2.56 MB) - after B

    int* slot_e    = (int*)(rec_vg + N_EDGES);     // N_INC
    int* slot_vhg  = slot_e   + N_INC;             // N_INC
    int* slot_vg   = slot_vhg + N_INC;             // N_EDGES
    // zeroed int region:
    int* deg_e     = slot_vg  + N_EDGES;           // N_HGE
    int* cur_e     = deg_e    + N_HGE;             // N_HGE
    int* deg_vhg   = cur_e    + N_HGE;             // N_VERTS
    int* cur_vhg   = deg_vhg  + N_VERTS;           // N_VERTS
    int* deg_vg    = cur_vhg  + N_VERTS;           // N_VERTS
    int* cur_vg    = deg_vg   + N_VERTS;           // N_VERTS
    int* bcur_e    = cur_vg   + N_VERTS;           // NB_E
    int* bcur_vhg  = bcur_e   + NB_E;              // NB_V
    int* bcur_vg   = bcur_vhg + NB_V;              // NB_V
    // not zeroed:
    int* off_e     = bcur_vg  + NB_V;              // N_HGE
    int* off_vhg   = off_e    + N_HGE;             // N_VERTS
    int* off_vg    = off_vhg  + N_VERTS;           // N_VERTS

    const size_t zero_elems = 2 * (size_t)N_HGE + 4 * (size_t)N_VERTS
                            + NB_E + 2 * NB_V;
    hipMemsetAsync(deg_e, 0, zero_elems * sizeof(int), stream);

    // ---- CSR build ----
    const int pair_blocks = (N_INC + 255) / 256;
    count_kernel<<<pair_blocks, 256, 0, stream>>>(hg_v, hg_e, g_dst,
                                                  deg_e, deg_vhg, deg_vg);
    scan3_kernel<<<3, 1024, 0, stream>>>(deg_e, off_e, deg_vhg, off_vhg,
                                         deg_vg, off_vg);
    const int partA_blocks = (N_INC + PAIRS_PER_BLOCK - 1) / PAIRS_PER_BLOCK;
    partitionA_kernel<<<partA_blocks, 256, 0, stream>>>(
        hg_v, hg_e, g_src, g_dst, off_e, off_vhg, off_vg,
        bcur_e, bcur_vhg, bcur_vg, rec_e, rec_vhg, rec_vg);
    partitionB_kernel<<<GRID_B, 256, 0, stream>>>(
        rec_e, rec_vhg, rec_vg, off_e, off_vhg, off_vg,
        cur_e, cur_vhg, cur_vg, slot_e, slot_vhg, slot_vg);

    // ---- MLP (after B: h aliases rec region) ----
    mlp_kernel<<<N_VERTS / VPB, 256, 0, stream>>>(x, W1, b1, W2, b2, h);

    // ---- v2e gather ----
    const int ge_blocks = (int)(((size_t)N_HGE * 64 + 255) / 256);
    gather_e_kernel<<<ge_blocks, 256, 0, stream>>>(slot_e, off_e, deg_e, h, e_feat);

    // ---- fused e2v + graph gather + finalize ----
    const int vo_blocks = (int)(((size_t)N_VERTS * 64 + 255) / 256);
    vertex_out_kernel<<<vo_blocks, 256, 0, stream>>>(slot_vhg, off_vhg, deg_vhg,
                                                     slot_vg, off_vg, deg_vg,
                                                     e_feat, h, w, out);
}